// Round 3
// baseline (380.244 us; speedup 1.0000x reference)
//
#include <hip/hip_runtime.h>
#include <hip/hip_bf16.h>

#define NN   207
#define BB   8
#define TT   12
#define EE   64
#define FFD  256
#define NGH  8
#define GALPHA 0.2f
#define GNEG  -9e15f

// LDS layout (float/u32 units). f32 bufs stride 68 (bank-safe), bf16 stride 72.
#define SRD   68
#define SRD16 72
#define L_OUT 0
#define L_QQ  816
#define L_CTX 1632
#define L_X1  2448
#define L_QB  3264   // bf16 [12][72] = 432 slots
#define L_KB  3696
#define L_VB  4128
#define L_SC  4560   // 4 heads * 144
#define L_GW  5136   // 64 W2 + 16 a + 16 b
#define L_A   5232   // GAT xs_pk (2484 u32)  |  XF: ff bf16 (1536) + part (3072)
#define L_FF  L_A
#define L_PART (L_A + 1536)
#define L_TOT (L_A + 4608)   // 9840 floats = 39360 B

__device__ __forceinline__ float wred_max(float v) {
#pragma unroll
  for (int o = 32; o >= 1; o >>= 1) v = fmaxf(v, __shfl_xor(v, o));
  return v;
}
__device__ __forceinline__ float wred_sum(float v) {
#pragma unroll
  for (int o = 32; o >= 1; o >>= 1) v += __shfl_xor(v, o);
  return v;
}
__device__ __forceinline__ float lo_f(unsigned u) { return __uint_as_float(u << 16); }
__device__ __forceinline__ float hi_f(unsigned u) { return __uint_as_float(u & 0xffff0000u); }
__device__ __forceinline__ unsigned pk2(float a, float b) {
  unsigned la = (unsigned)__bfloat16_as_ushort(__float2bfloat16(a));
  unsigned lb = (unsigned)__bfloat16_as_ushort(__float2bfloat16(b));
  return la | (lb << 16);
}
__device__ __forceinline__ unsigned short bf16u(float a) {
  return __bfloat16_as_ushort(__float2bfloat16(a));
}
#define UNPK8(U, f) { (f)[0]=lo_f((U).x); (f)[1]=hi_f((U).x); (f)[2]=lo_f((U).y); (f)[3]=hi_f((U).y); \
                      (f)[4]=lo_f((U).z); (f)[5]=hi_f((U).z); (f)[6]=lo_f((U).w); (f)[7]=hi_f((U).w); }

__global__ __launch_bounds__(256, 4) void fused_gat_xf_kernel(
    const float* __restrict__ x,        const int* __restrict__ adj,
    const float* __restrict__ gat_W2,   const float* __restrict__ gat_a,
    const float* __restrict__ gat_b,    const float* __restrict__ conv1_w,
    const float* __restrict__ conv1_b,  const float* __restrict__ temb,
    const float* __restrict__ Wq, const float* __restrict__ Wk,
    const float* __restrict__ Wv, const float* __restrict__ Wo,
    const float* __restrict__ bo,
    const float* __restrict__ ln1_g, const float* __restrict__ ln1_b,
    const float* __restrict__ ln2_g, const float* __restrict__ ln2_b,
    const float* __restrict__ ff_w1, const float* __restrict__ ff_b1,
    const float* __restrict__ ff_w2, const float* __restrict__ ff_b2,
    const float* __restrict__ lng, const float* __restrict__ lnb,
    const float* __restrict__ conv2_w, const float* __restrict__ conv2_b,
    const float* __restrict__ conv3_w, const float* __restrict__ conv3_b,
    float* __restrict__ fout)
{
  __shared__ float lds[L_TOT];
  unsigned*       au   = (unsigned*)lds;
  unsigned short* sh16 = (unsigned short*)lds;

  const int bn   = blockIdx.x;
  const int b    = bn / NN;
  const int i    = bn % NN;
  const int tid  = threadIdx.x;
  const int lane = tid & 63;
  const int wid  = tid >> 6;

  // ---- stage x[b] packed bf16x2 (both channels) as xs_pk[t][n]; GAT params ----
  const float* xb = x + b * 2 * NN * TT;
  for (int idx = tid; idx < NN * TT; idx += 256) {
    const int n = idx / TT, t = idx % TT;
    au[L_A + t * NN + n] = pk2(xb[idx], xb[NN * TT + idx]);
  }
  if (tid < 64) lds[L_GW + tid] = gat_W2[tid];
  if (tid < 16) { lds[L_GW + 64 + tid] = gat_a[tid]; lds[L_GW + 80 + tid] = gat_b[tid]; }
  __syncthreads();

  // ---- GAT: wave w owns t in {w, w+4, w+8}; lanes span j (4 j's/lane) ----
  int   row0[4], row1[4];
  float aokf[4];
  bool  jv[4];
  {
    const int NSQ = NN * NN;
#pragma unroll
    for (int q = 0; q < 4; ++q) {
      const int j = lane + 64 * q;
      jv[q] = (j < NN);
      const int jj = jv[q] ? j : 0;
      const int r0 = 2 * (i * NN + jj), r1 = r0 + 1;
      row0[q] = (r0 < NSQ) ? (r0 / NN) : ((r0 - NSQ) % NN);
      row1[q] = (r1 < NSQ) ? (r1 / NN) : ((r1 - NSQ) % NN);
      aokf[q] = (jv[q] && adj[(b * NN + i) * NN + jj] > 0) ? 1.f : 0.f;
    }
  }

  float acc0[3] = {0.f, 0.f, 0.f}, acc1[3] = {0.f, 0.f, 0.f};
#pragma unroll
  for (int tk = 0; tk < 3; ++tk) {
    const int t = wid + 4 * tk;
    const unsigned* xst = au + L_A + t * NN;
    float xr00[4], xr01[4], xr10[4], xr11[4], xj0[4], xj1[4];
#pragma unroll
    for (int q = 0; q < 4; ++q) {
      const int j = jv[q] ? (lane + 64 * q) : 0;
      const unsigned u0 = xst[row0[q]], u1 = xst[row1[q]], uj = xst[j];
      xr00[q] = lo_f(u0); xr01[q] = hi_f(u0);
      xr10[q] = lo_f(u1); xr11[q] = hi_f(u1);
      xj0[q]  = lo_f(uj); xj1[q]  = hi_f(uj);
    }
    for (int h = 0; h < NGH; ++h) {
      const float w0 = lds[L_GW + h*8 + 0], w1_ = lds[L_GW + h*8 + 1];
      const float w2_= lds[L_GW + h*8 + 2], w3  = lds[L_GW + h*8 + 3];
      const float w4 = lds[L_GW + h*8 + 4], w5  = lds[L_GW + h*8 + 5];
      const float w6 = lds[L_GW + h*8 + 6], w7  = lds[L_GW + h*8 + 7];
      const float a0 = lds[L_GW + 64 + h*2], a1 = lds[L_GW + 64 + h*2 + 1];
      float ev[4];
#pragma unroll
      for (int q = 0; q < 4; ++q) {
        float wx0 = xr00[q]*w0 + xr01[q]*w2_ + xr10[q]*w4 + xr11[q]*w6;
        float wx1 = xr00[q]*w1_ + xr01[q]*w3 + xr10[q]*w5 + xr11[q]*w7;
        wx0 = (wx0 > 0.f) ? wx0 : GALPHA * wx0;
        wx1 = (wx1 > 0.f) ? wx1 : GALPHA * wx1;
        float e = a0 * wx0 + a1 * wx1;
        e = (aokf[q] > 0.f) ? e : GNEG;
        ev[q] = jv[q] ? e : -INFINITY;
      }
      float m = fmaxf(fmaxf(ev[0], ev[1]), fmaxf(ev[2], ev[3]));
      m = wred_max(m);
      float s0 = 0.f, s1 = 0.f, s2 = 0.f;
#pragma unroll
      for (int q = 0; q < 4; ++q) {
        const float ex = jv[q] ? __expf(ev[q] - m) : 0.f;
        s0 += ex; s1 += ex * xj0[q]; s2 += ex * xj1[q];
      }
      s0 = wred_sum(s0); s1 = wred_sum(s1); s2 = wred_sum(s2);
      const float inv = 1.f / s0;
      acc0[tk] += tanhf(s1 * inv + lds[L_GW + 80 + h*2]);
      acc1[tk] += tanhf(s2 * inv + lds[L_GW + 80 + h*2 + 1]);
    }
  }

  // ---- conv1 epilogue -> OUT ----
  {
    const float c1w0 = conv1_w[lane],       c1w1 = conv1_w[64 + lane];
    const float c1w2 = conv1_w[128 + lane], c1w3 = conv1_w[192 + lane];
    const float c1b  = conv1_b[lane];
#pragma unroll
    for (int tk = 0; tk < 3; ++tk) {
      const int t = wid + 4 * tk;
      const unsigned up = au[L_A + t * NN + i];
      const float g0 = acc0[tk] * (1.f / NGH), g1 = acc1[tk] * (1.f / NGH);
      lds[L_OUT + t*SRD + lane] = lo_f(up)*c1w0 + hi_f(up)*c1w1 + g0*c1w2 + g1*c1w3 + c1b;
    }
  }
  __syncthreads();

  // ---- transformer layers ----
  for (int l = 0; l < 2; ++l) {
    const float* wq = Wq + l*4096; const float* wk = Wk + l*4096;
    const float* wv = Wv + l*4096; const float* wo = Wo + l*4096;
    const float* w1 = ff_w1 + l*EE*FFD; const float* pb1 = ff_b1 + l*FFD;
    const float* w2 = ff_w2 + l*FFD*EE; const float* pb2 = ff_b2 + l*EE;

    // qq = out + temb
    {
      const int e = tid & 63;
#pragma unroll
      for (int tt = 0; tt < 3; ++tt) {
        const int t = 3*wid + tt;
        lds[L_QQ + t*SRD + e] = lds[L_OUT + t*SRD + e] + temb[t*EE + e];
      }
    }
    __syncthreads();

    // QKV: thread owns cols (c in Q, K, V) x t-triple. All 4 waves active.
    {
      const int c = tid & 63;
      float aq[3] = {0,0,0}, ak[3] = {0,0,0}, av[3] = {0,0,0};
      for (int kb = 0; kb < 16; ++kb) {
        float a0v[4], a1v[4], a2v[4];
        *(float4*)a0v = *(const float4*)&lds[L_QQ + (3*wid+0)*SRD + 4*kb];
        *(float4*)a1v = *(const float4*)&lds[L_QQ + (3*wid+1)*SRD + 4*kb];
        *(float4*)a2v = *(const float4*)&lds[L_QQ + (3*wid+2)*SRD + 4*kb];
#pragma unroll
        for (int kk = 0; kk < 4; ++kk) {
          const int k = 4*kb + kk;
          const float wqv = wq[k*EE + c], wkv = wk[k*EE + c], wvv = wv[k*EE + c];
          aq[0] += a0v[kk]*wqv; aq[1] += a1v[kk]*wqv; aq[2] += a2v[kk]*wqv;
          ak[0] += a0v[kk]*wkv; ak[1] += a1v[kk]*wkv; ak[2] += a2v[kk]*wkv;
          av[0] += a0v[kk]*wvv; av[1] += a1v[kk]*wvv; av[2] += a2v[kk]*wvv;
        }
      }
#pragma unroll
      for (int tt = 0; tt < 3; ++tt) {
        const int t = 3*wid + tt;
        sh16[2*L_QB + t*SRD16 + c] = bf16u(aq[tt]);
        sh16[2*L_KB + t*SRD16 + c] = bf16u(ak[tt]);
        sh16[2*L_VB + t*SRD16 + c] = bf16u(av[tt]);
      }
    }
    __syncthreads();

    // Attention: wave h owns head h; wave-local (no block barriers inside).
    {
      const int h = wid;
      if (lane < 48) {
        const int t = lane >> 2, s0 = 3*(lane & 3);
        const uint4 qa = *(const uint4*)&sh16[2*L_QB + t*SRD16 + h*16];
        const uint4 qb = *(const uint4*)&sh16[2*L_QB + t*SRD16 + h*16 + 8];
        float qf[16]; UNPK8(qa, qf); UNPK8(qb, qf + 8);
#pragma unroll
        for (int ss = 0; ss < 3; ++ss) {
          const int s = s0 + ss;
          const uint4 ka = *(const uint4*)&sh16[2*L_KB + s*SRD16 + h*16];
          const uint4 kc = *(const uint4*)&sh16[2*L_KB + s*SRD16 + h*16 + 8];
          float kf[16]; UNPK8(ka, kf); UNPK8(kc, kf + 8);
          float d = 0.f;
#pragma unroll
          for (int xq = 0; xq < 16; ++xq) d += qf[xq]*kf[xq];
          lds[L_SC + h*144 + t*12 + s] = d * 0.25f;
        }
      }
      __builtin_amdgcn_wave_barrier();
      if (lane < 12) {
        float* row = &lds[L_SC + h*144 + lane*12];
        float m = row[0];
#pragma unroll
        for (int s = 1; s < 12; ++s) m = fmaxf(m, row[s]);
        float ex[12]; float sum = 0.f;
#pragma unroll
        for (int s = 0; s < 12; ++s) { ex[s] = __expf(row[s] - m); sum += ex[s]; }
        const float inv = 1.f / sum;
#pragma unroll
        for (int s = 0; s < 12; ++s) row[s] = ex[s] * inv;
      }
      __builtin_amdgcn_wave_barrier();
      {
        const int d = lane & 15, tq = lane >> 4;
#pragma unroll
        for (int tt = 0; tt < 3; ++tt) {
          const int t = tq + 4*tt;
          float cacc = 0.f;
#pragma unroll
          for (int s = 0; s < 12; ++s) {
            const float p = lds[L_SC + h*144 + t*12 + s];
            const unsigned uv = au[L_VB + s*36 + h*8 + (d >> 1)];
            cacc += p * ((d & 1) ? hi_f(uv) : lo_f(uv));
          }
          lds[L_CTX + t*SRD + h*16 + d] = cacc;
        }
      }
    }
    __syncthreads();

    // Wo + bias + residual(qq) -> X1
    {
      const int e = tid & 63;
      float acc[3] = {0,0,0};
      for (int kb = 0; kb < 16; ++kb) {
        float a0v[4], a1v[4], a2v[4];
        *(float4*)a0v = *(const float4*)&lds[L_CTX + (3*wid+0)*SRD + 4*kb];
        *(float4*)a1v = *(const float4*)&lds[L_CTX + (3*wid+1)*SRD + 4*kb];
        *(float4*)a2v = *(const float4*)&lds[L_CTX + (3*wid+2)*SRD + 4*kb];
#pragma unroll
        for (int kk = 0; kk < 4; ++kk) {
          const float wov = wo[(4*kb+kk)*EE + e];
          acc[0] += a0v[kk]*wov; acc[1] += a1v[kk]*wov; acc[2] += a2v[kk]*wov;
        }
      }
#pragma unroll
      for (int tt = 0; tt < 3; ++tt) {
        const int t = 3*wid + tt;
        lds[L_X1 + t*SRD + e] = acc[tt] + bo[l*EE + e] + lds[L_QQ + t*SRD + e];
      }
    }
    __syncthreads();

    // LN1
    for (int tk = 0; tk < 3; ++tk) {
      const int t = wid + 4*tk;
      float v = lds[L_X1 + t*SRD + lane];
      const float mu = wred_sum(v) * (1.f/64);
      const float d = v - mu;
      const float var = wred_sum(d*d) * (1.f/64);
      lds[L_X1 + t*SRD + lane] = d * rsqrtf(var + 1e-5f) * ln1_g[l*EE + lane] + ln1_b[l*EE + lane];
    }
    __syncthreads();

    // FF1 + relu -> ff (bf16). Thread owns f-quad x t-triple.
    {
      const int f0 = 4 * (tid & 63);
      float ac0[4] = {0,0,0,0}, ac1[4] = {0,0,0,0}, ac2[4] = {0,0,0,0};
      for (int kb = 0; kb < 16; ++kb) {
        float a0v[4], a1v[4], a2v[4];
        *(float4*)a0v = *(const float4*)&lds[L_X1 + (3*wid+0)*SRD + 4*kb];
        *(float4*)a1v = *(const float4*)&lds[L_X1 + (3*wid+1)*SRD + 4*kb];
        *(float4*)a2v = *(const float4*)&lds[L_X1 + (3*wid+2)*SRD + 4*kb];
#pragma unroll
        for (int kk = 0; kk < 4; ++kk) {
          float wvv[4];
          *(float4*)wvv = *(const float4*)&w1[(4*kb+kk)*FFD + f0];
#pragma unroll
          for (int ff = 0; ff < 4; ++ff) {
            ac0[ff] += a0v[kk]*wvv[ff];
            ac1[ff] += a1v[kk]*wvv[ff];
            ac2[ff] += a2v[kk]*wvv[ff];
          }
        }
      }
      float bv[4]; *(float4*)bv = *(const float4*)&pb1[f0];
#pragma unroll
      for (int tt = 0; tt < 3; ++tt) {
        const int t = 3*wid + tt;
        float* ac = (tt == 0) ? ac0 : (tt == 1) ? ac1 : ac2;
        const float r0 = fmaxf(ac[0] + bv[0], 0.f), r1 = fmaxf(ac[1] + bv[1], 0.f);
        const float r2 = fmaxf(ac[2] + bv[2], 0.f), r3 = fmaxf(ac[3] + bv[3], 0.f);
        au[L_FF + t*128 + (f0 >> 1)]     = pk2(r0, r1);
        au[L_FF + t*128 + (f0 >> 1) + 1] = pk2(r2, r3);
      }
    }
    __syncthreads();

    // FF2: wave = k-slice of 64; lane owns e-pair x 6 t's -> partials
    {
      const int e0 = 2 * (lane & 31);
      const int th = lane >> 5;
      float acc[6][2] = {};
      for (int c = 0; c < 8; ++c) {
        float2 wv2[8];
#pragma unroll
        for (int kk = 0; kk < 8; ++kk)
          wv2[kk] = *(const float2*)&w2[(wid*64 + c*8 + kk)*EE + e0];
#pragma unroll
        for (int tt = 0; tt < 6; ++tt) {
          const int t = th*6 + tt;
          const uint4 U = *(const uint4*)&au[L_FF + t*128 + wid*32 + c*4];
          float fv[8]; UNPK8(U, fv);
#pragma unroll
          for (int kk = 0; kk < 8; ++kk) {
            acc[tt][0] += fv[kk]*wv2[kk].x;
            acc[tt][1] += fv[kk]*wv2[kk].y;
          }
        }
      }
#pragma unroll
      for (int tt = 0; tt < 6; ++tt) {
        const int t = th*6 + tt;
        *(float2*)&lds[L_PART + wid*768 + t*EE + e0] = make_float2(acc[tt][0], acc[tt][1]);
      }
    }
    __syncthreads();

    // combine partials + b2 + residual(x1) ; LN2 ; out = LN3(blk + out)
    for (int tk = 0; tk < 3; ++tk) {
      const int t = wid + 4*tk;
      float v = lds[L_PART + t*EE + lane] + lds[L_PART + 768 + t*EE + lane]
              + lds[L_PART + 1536 + t*EE + lane] + lds[L_PART + 2304 + t*EE + lane]
              + pb2[lane] + lds[L_X1 + t*SRD + lane];
      float mu = wred_sum(v) * (1.f/64);
      float d = v - mu;
      float var = wred_sum(d*d) * (1.f/64);
      const float blk = d * rsqrtf(var + 1e-5f) * ln2_g[l*EE + lane] + ln2_b[l*EE + lane];
      float w = blk + lds[L_OUT + t*SRD + lane];
      mu = wred_sum(w) * (1.f/64);
      d = w - mu;
      var = wred_sum(d*d) * (1.f/64);
      lds[L_OUT + t*SRD + lane] = d * rsqrtf(var + 1e-5f) * lng[l*EE + lane] + lnb[l*EE + lane];
    }
    __syncthreads();
  }

  // ---- final conv2 (time mix) + relu + conv3 (embed contraction) ----
  float xt[12];
#pragma unroll
  for (int t = 0; t < 12; ++t) xt[t] = lds[L_OUT + t*SRD + lane];
  const float c3w = conv3_w[lane];
  for (int o = wid; o < 12; o += 4) {
    float a = conv2_b[o];
#pragma unroll
    for (int t = 0; t < 12; ++t) a += xt[t] * conv2_w[o*TT + t];
    a = fmaxf(a, 0.f);
    const float s = wred_sum(a * c3w);
    if (lane == 0) fout[bn*TT + o] = s + conv3_b[0];
  }
}

// ---------------------------------------------------------------------------
extern "C" void kernel_launch(void* const* d_in, const int* in_sizes, int n_in,
                              void* d_out, int out_size, void* d_ws, size_t ws_size,
                              hipStream_t stream) {
  const float* x       = (const float*)d_in[0];
  const int*   adj     = (const int*)  d_in[1];
  const float* gat_W2  = (const float*)d_in[2];
  const float* gat_a   = (const float*)d_in[3];
  const float* gat_b   = (const float*)d_in[4];
  const float* conv1_w = (const float*)d_in[5];
  const float* conv1_b = (const float*)d_in[6];
  const float* temb    = (const float*)d_in[7];
  const float* Wq      = (const float*)d_in[8];
  const float* Wk      = (const float*)d_in[9];
  const float* Wv      = (const float*)d_in[10];
  const float* Wo      = (const float*)d_in[11];
  const float* bo      = (const float*)d_in[12];
  const float* ln1_g   = (const float*)d_in[13];
  const float* ln1_b   = (const float*)d_in[14];
  const float* ln2_g   = (const float*)d_in[15];
  const float* ln2_b   = (const float*)d_in[16];
  const float* ff_w1   = (const float*)d_in[17];
  const float* ff_b1   = (const float*)d_in[18];
  const float* ff_w2   = (const float*)d_in[19];
  const float* ff_b2   = (const float*)d_in[20];
  const float* lng     = (const float*)d_in[21];
  const float* lnb     = (const float*)d_in[22];
  const float* conv2_w = (const float*)d_in[23];
  const float* conv2_b = (const float*)d_in[24];
  const float* conv3_w = (const float*)d_in[25];
  const float* conv3_b = (const float*)d_in[26];

  float* fout = (float*)d_out;

  fused_gat_xf_kernel<<<BB*NN, 256, 0, stream>>>(
      x, adj, gat_W2, gat_a, gat_b, conv1_w, conv1_b, temb,
      Wq, Wk, Wv, Wo, bo, ln1_g, ln1_b, ln2_g, ln2_b,
      ff_w1, ff_b1, ff_w2, ff_b2, lng, lnb,
      conv2_w, conv2_b, conv3_w, conv3_b, fout);
}